// Round 1
// 1921.808 us; speedup vs baseline: 1.0987x; 1.0987x over previous
//
#include <hip/hip_runtime.h>
#include <stdint.h>

#define HH 128
#define WW 128
#define NIMG 32
#define CH 16
#define TILE 16
#define LW 20            // 16 + 2*2 halo
#define LA (LW * LW)     // 400 floats per channel plane
#define NUM_ITER 30
#define THR 0.1f
#define HWSZ (HH * WW)

// ---------------- init: build 16-ch cell state from 10-ch input ----------------
__global__ __launch_bounds__(256) void init_kernel(const float* __restrict__ inp,
                                                   float* __restrict__ cell) {
    int i = blockIdx.x * 256 + threadIdx.x;
    if (i >= NIMG * CH * HWSZ) return;
    int hw = i % HWSZ;
    int c  = (i / HWSZ) % CH;
    int n  = i / (CH * HWSZ);
    float v;
    if (c == 0)       v = 1.0f - inp[(n * 10 + 0) * HWSZ + hw];
    else if (c <= 10) v = inp[(n * 10 + (c - 1)) * HWSZ + hw];
    else              v = 0.0f;
    cell[i] = v;
}

// ---------------- w2 [16,48] -> w2t [48,16] -------------
__global__ void transpose_w2(const float* __restrict__ w2, float* __restrict__ w2t) {
    int i = threadIdx.x;
    if (i < 768) {
        int o = i / 16, k = i % 16;
        w2t[o * 16 + k] = w2[k * 48 + o];
    }
}

// perception: p[0..15]=center, p[16..31]=sobel-x, p[32..47]=sobel-y
__device__ __forceinline__ void perception_at(const float* cs, int base, float* p) {
#pragma unroll
    for (int c = 0; c < CH; ++c) {
        const float* cc = cs + c * LA;
        float c00 = cc[base - LW - 1], c01 = cc[base - LW], c02 = cc[base - LW + 1];
        float c10 = cc[base - 1],      c11 = cc[base],      c12 = cc[base + 1];
        float c20 = cc[base + LW - 1], c21 = cc[base + LW], c22 = cc[base + LW + 1];
        p[c]      = c11;
        p[16 + c] = (c02 - c00 + 2.0f * (c12 - c10) + c22 - c20) * 0.125f;
        p[32 + c] = (c20 - c00 + 2.0f * (c21 - c01) + c22 - c02) * 0.125f;
    }
}

__device__ __forceinline__ float dot48(const float* __restrict__ w, const float* p) {
    float a0 = 0.f, a1 = 0.f, a2 = 0.f, a3 = 0.f;
#pragma unroll
    for (int c = 0; c < 48; c += 4) {
        a0 = fmaf(w[c + 0], p[c + 0], a0);
        a1 = fmaf(w[c + 1], p[c + 1], a1);
        a2 = fmaf(w[c + 2], p[c + 2], a2);
        a3 = fmaf(w[c + 3], p[c + 3], a3);
    }
    return (a0 + a1) + (a2 + a3);
}

// ---------------- one fused CA step ----------------
// Carried state: ungated cur (16ch) + pre-mask bits.
// R4 restructure (latency-bound: VALUBusy 36%, HBM 16%, Occ 38% = 3 blk/CU):
//  * raw ch0 staged into a 17th LDS plane; ch1..15 global loads + pre-bit load
//    pre-issued into REGISTERS before the first barrier (T14 load-early /
//    write-late) -> one vmcnt drain per step instead of two serial ones.
//  * gate factor is thread-local (old gm[] was written and read by the same
//    thread) -> B and C fused, gm LDS array gone -> 2 barriers/step, not 3.
//  * launch_bounds(256,4): 128-reg combined budget -> 4 blocks/CU (LDS
//    27.2KB x4 = 109KB). Peak liveness ~p[48]+cur[16]+addr ~ 100 regs.
__global__ __launch_bounds__(256, 4) void step_kernel(
    const float* __restrict__ cin, float* __restrict__ cout,
    const uint8_t* __restrict__ pre_in, uint8_t* __restrict__ pre_out,
    const float* __restrict__ w1, const float* __restrict__ w2t,
    int gate) {

    __shared__ float cs[(CH + 1) * LA];  // planes 0..15 = gated cell; 16 = raw ch0

    const int tid = threadIdx.x;
    const int tx = tid & 15, ty = tid >> 4;
    const int bx = blockIdx.x * TILE, by = blockIdx.y * TILE;
    const int n = blockIdx.z;
    const float* cbase = cin + (size_t)n * CH * HWSZ;
    const uint8_t* pbase = pre_in + (size_t)n * HWSZ;

    // ---- hoisted coords: full 20x20 positions (raw ch0), two per thread ----
    const int lyA = tid / 20, lxA = tid % 20;
    const int gyA = by + lyA - 2, gxA = bx + lxA - 2;
    const bool okA = ((unsigned)gyA < HH) && ((unsigned)gxA < WW);
    const int offA = gyA * WW + gxA;

    const int rB = tid + 256;                  // valid when tid < 144
    const int lyB = rB / 20, lxB = rB % 20;
    const int gyB = by + lyB - 2, gxB = bx + lxB - 2;
    const bool okB = ((unsigned)gyB < HH) && ((unsigned)gxB < WW);
    const int offB = gyB * WW + gxB;

    // ---- hoisted coords: 18x18 region positions, two per thread ----
    const int j0 = tid;                        // always < 324
    const int jy0 = j0 / 18, jx0 = j0 % 18;
    const int gy0 = by + jy0 - 1, gx0 = bx + jx0 - 1;
    const bool ok0 = ((unsigned)gy0 < HH) && ((unsigned)gx0 < WW);
    const int goff0 = gy0 * WW + gx0;
    const int lpos0 = (jy0 + 1) * LW + (jx0 + 1);

    const int j1 = tid + 256;                  // valid when tid < 68
    const int jy1 = j1 / 18, jx1 = j1 % 18;
    const int gy1 = by + jy1 - 1, gx1 = bx + jx1 - 1;
    const bool ok1 = ((unsigned)gy1 < HH) && ((unsigned)gx1 < WW);
    const int goff1 = gy1 * WW + gx1;
    const int lpos1 = (jy1 + 1) * LW + (jx1 + 1);
    const bool hasB = (tid < 68);

    // ---- A: stage raw ch0 (plane 16) AND pre-issue all other global loads ----
    cs[CH * LA + tid] = okA ? cbase[offA] : 0.0f;
    if (tid < 144) cs[CH * LA + rB] = okB ? cbase[offB] : 0.0f;

    float st0[CH - 1];
    {
        const float* gp = cbase + goff0;
#pragma unroll
        for (int c = 1; c < CH; ++c) st0[c - 1] = ok0 ? gp[c * HWSZ] : 0.0f;
    }
    int pv0 = 1;
    if (gate) pv0 = ok0 ? (int)pbase[goff0] : 0;

    float st1[CH - 1];
    int pv1 = 1;
    if (hasB) {
        const float* gp = cbase + goff1;
#pragma unroll
        for (int c = 1; c < CH; ++c) st1[c - 1] = ok1 ? gp[c * HWSZ] : 0.0f;
        if (gate) pv1 = ok1 ? (int)pbase[goff1] : 0;
    }
    __syncthreads();   // single drain: ch0 stores + all pre-issued loads in flight

    // ---- B+C fused: gate factor from raw plane 16, gated writes to planes 0..15 ----
    {
        const float* rp = cs + CH * LA;
        float pm = -1e30f;
#pragma unroll
        for (int dy = -1; dy <= 1; ++dy)
#pragma unroll
            for (int dx = -1; dx <= 1; ++dx)
                pm = fmaxf(pm, rp[lpos0 + dy * LW + dx]);
        float g0 = 1.0f;
        if (gate) g0 = (pv0 && pm > THR) ? 1.0f : 0.0f;
        cs[lpos0] = rp[lpos0] * g0;
#pragma unroll
        for (int c = 1; c < CH; ++c) cs[c * LA + lpos0] = st0[c - 1] * g0;
    }
    if (hasB) {
        const float* rp = cs + CH * LA;
        float pm = -1e30f;
#pragma unroll
        for (int dy = -1; dy <= 1; ++dy)
#pragma unroll
            for (int dx = -1; dx <= 1; ++dx)
                pm = fmaxf(pm, rp[lpos1 + dy * LW + dx]);
        float g1 = 1.0f;
        if (gate) g1 = (pv1 && pm > THR) ? 1.0f : 0.0f;
        cs[lpos1] = rp[lpos1] * g1;
#pragma unroll
        for (int c = 1; c < CH; ++c) cs[c * LA + lpos1] = st1[c - 1] * g1;
    }
    __syncthreads();

    // ---- D: pre(i) bits, perception, matmuls (inner 16x16 only) ----
    const int base = (ty + 2) * LW + (tx + 2);
    float pm = -1e30f;
#pragma unroll
    for (int dy = -1; dy <= 1; ++dy)
#pragma unroll
        for (int dx = -1; dx <= 1; ++dx)
            pm = fmaxf(pm, cs[base + dy * LW + dx]);
    pre_out[(size_t)n * HWSZ + (size_t)(by + ty) * WW + (bx + tx)] = (pm > THR) ? 1 : 0;

    float p[48];
    perception_at(cs, base, p);

    float cur[16];
#pragma unroll
    for (int k = 0; k < 16; ++k) cur[k] = p[k];   // residual

#pragma unroll 4
    for (int o = 0; o < 48; ++o) {
        float hv = fmaxf(dot48(w1 + o * 48, p), 0.0f);
#pragma unroll
        for (int k = 0; k < 16; ++k) cur[k] = fmaf(w2t[o * 16 + k], hv, cur[k]);
    }

    float* obase = cout + (size_t)n * CH * HWSZ + (size_t)(by + ty) * WW + (bx + tx);
#pragma unroll
    for (int k = 0; k < 16; ++k)
        obase[k * HWSZ] = cur[k];
}

// ---------------- final: apply gate(30), emit channels 1..10 ----------------
__global__ __launch_bounds__(256) void final_kernel(
    const float* __restrict__ cur, const uint8_t* __restrict__ pre,
    float* __restrict__ out) {
    int i = blockIdx.x * 256 + threadIdx.x;        // over NIMG*H*W
    if (i >= NIMG * HWSZ) return;
    int x = i % WW, y = (i / WW) % HH, n = i / HWSZ;
    const float* c0 = cur + (size_t)n * CH * HWSZ;
    float pm = -1e30f;
    for (int dy = -1; dy <= 1; ++dy) {
        int yy = y + dy;
        if ((unsigned)yy >= HH) continue;
        for (int dx = -1; dx <= 1; ++dx) {
            int xx = x + dx;
            if ((unsigned)xx >= WW) continue;
            pm = fmaxf(pm, c0[yy * WW + xx]);
        }
    }
    const bool alive = pre[i] && (pm > THR);
    float* ob = out + (size_t)n * 10 * HWSZ + y * WW + x;
#pragma unroll
    for (int k = 1; k <= 10; ++k)
        ob[(k - 1) * HWSZ] = alive ? c0[k * HWSZ + y * WW + x] : 0.0f;
}

extern "C" void kernel_launch(void* const* d_in, const int* in_sizes, int n_in,
                              void* d_out, int out_size, void* d_ws, size_t ws_size,
                              hipStream_t stream) {
    const float* inp = (const float*)d_in[0];
    const float* w1  = (const float*)d_in[1];
    const float* w2  = (const float*)d_in[2];
    float* out = (float*)d_out;

    const size_t SE = (size_t)NIMG * CH * HWSZ;    // 8,388,608 floats
    float* bufA = (float*)d_ws;
    float* bufB = bufA + SE;
    float* w2t  = bufB + SE;
    uint8_t* bitsA = (uint8_t*)(w2t + 768);
    uint8_t* bitsB = bitsA + (size_t)NIMG * HWSZ;

    init_kernel<<<((int)SE + 255) / 256, 256, 0, stream>>>(inp, bufA);
    transpose_w2<<<1, 768, 0, stream>>>(w2, w2t);

    dim3 grid(WW / TILE, HH / TILE, NIMG);
    float* src = bufA;
    float* dst = bufB;
    uint8_t* pin = bitsB;   // unused on first iter (gate=0)
    uint8_t* pout = bitsA;
    for (int it = 0; it < NUM_ITER; ++it) {
        step_kernel<<<grid, 256, 0, stream>>>(src, dst, pin, pout, w1, w2t,
                                              it == 0 ? 0 : 1);
        float* t = src; src = dst; dst = t;
        uint8_t* tb = pin; pin = pout; pout = tb;
    }
    // after loop: src = cur(30), pin = pre(30) bits
    final_kernel<<<(NIMG * HWSZ + 255) / 256, 256, 0, stream>>>(src, pin, out);
}

// Round 2
// 1477.376 us; speedup vs baseline: 1.4293x; 1.3008x over previous
//
#include <hip/hip_runtime.h>
#include <stdint.h>

#define HH 128
#define WW 128
#define NIMG 32
#define CH 16
#define TILE 16
#define LW 20            // 16 + 2*2 halo
#define LA (LW * LW)     // 400 floats per channel plane
#define NUM_ITER 30
#define THR 0.1f
#define HWSZ (HH * WW)

#define PSTR 52                    // P/H row stride in bf16 elems (104B: 26dw -> conflict-free-ish)
#define PL_OFF (256 * PSTR)        // Pl offset from Ph, in ushorts
#define SMEM_BYTES (2 * 256 * PSTR * 2)   // 53248 B -> 3 blocks/CU

typedef __attribute__((ext_vector_type(8))) short bf16x8;
typedef __attribute__((ext_vector_type(4))) float f32x4;
typedef __attribute__((ext_vector_type(4))) short sh4;

__device__ __forceinline__ unsigned short f2bf(float x) {
    union { float f; unsigned u; } v; v.f = x;
    return (unsigned short)((v.u + 0x7fffu + ((v.u >> 16) & 1u)) >> 16);  // RNE
}
__device__ __forceinline__ float bf2f(unsigned short h) {
    union { unsigned u; float f; } v; v.u = ((unsigned)h) << 16; return v.f;
}
__device__ __forceinline__ bf16x8 mk8(sh4 a, sh4 b) {
    bf16x8 r;
    r[0] = a.x; r[1] = a.y; r[2] = a.z; r[3] = a.w;
    r[4] = b.x; r[5] = b.y; r[6] = b.z; r[7] = b.w;
    return r;
}
__device__ __forceinline__ sh4 lds4(const unsigned short* p) {
    return *(const sh4*)p;
}

// ---------------- init: build 16-ch cell state from 10-ch input ----------------
__global__ __launch_bounds__(256) void init_kernel(const float* __restrict__ inp,
                                                   float* __restrict__ cell) {
    int i = blockIdx.x * 256 + threadIdx.x;
    if (i >= NIMG * CH * HWSZ) return;
    int hw = i % HWSZ;
    int c  = (i / HWSZ) % CH;
    int n  = i / (CH * HWSZ);
    float v;
    if (c == 0)       v = 1.0f - inp[(n * 10 + 0) * HWSZ + hw];
    else if (c <= 10) v = inp[(n * 10 + (c - 1)) * HWSZ + hw];
    else              v = 0.0f;
    cell[i] = v;
}

// ---------------- weight prepack: bf16 hi/lo split, A-fragment-friendly row-major ----
// w1h/w1l: [48][48] bf16 (row = out-ch, k = in-ch). w2h/w2l: [16][48].
__global__ void prepack(const float* __restrict__ w1, const float* __restrict__ w2,
                        unsigned short* __restrict__ w1h, unsigned short* __restrict__ w1l,
                        unsigned short* __restrict__ w2h, unsigned short* __restrict__ w2l) {
    int i = threadIdx.x;
    for (int k = i; k < 48 * 48; k += 256) {
        float f = w1[k];
        unsigned short h = f2bf(f);
        w1h[k] = h;
        w1l[k] = f2bf(f - bf2f(h));
    }
    for (int k = i; k < 16 * 48; k += 256) {
        float f = w2[k];
        unsigned short h = f2bf(f);
        w2h[k] = h;
        w2l[k] = f2bf(f - bf2f(h));
    }
}

// perception: p[0..15]=center, p[16..31]=sobel-x, p[32..47]=sobel-y
__device__ __forceinline__ void perception_at(const float* cs, int base, float* p) {
#pragma unroll
    for (int c = 0; c < CH; ++c) {
        const float* cc = cs + c * LA;
        float c00 = cc[base - LW - 1], c01 = cc[base - LW], c02 = cc[base - LW + 1];
        float c10 = cc[base - 1],      c11 = cc[base],      c12 = cc[base + 1];
        float c20 = cc[base + LW - 1], c21 = cc[base + LW], c22 = cc[base + LW + 1];
        p[c]      = c11;
        p[16 + c] = (c02 - c00 + 2.0f * (c12 - c10) + c22 - c20) * 0.125f;
        p[32 + c] = (c20 - c00 + 2.0f * (c21 - c01) + c22 - c02) * 0.125f;
    }
}

// ---------------- one fused CA step (MFMA matmuls) ----------------
// Phases A..C identical to the verified R1 kernel (stage+gate into cs, 17 planes).
// D: per-thread perception -> split-bf16 P staged to LDS (overlays cs) ->
//    w1 via mfma_f32_16x16x32_bf16 (3-product hi/lo split, K=48 zero-padded in regs)
//    -> h(relu) bf16 overlays P-hi -> w2 via mfma (2-product) -> +residual -> store.
// M = out-channels, N = pixels (wave wv owns pixels [64*wv, 64*wv+64)).
__global__ __launch_bounds__(256, 3) void step_kernel(
    const float* __restrict__ cin, float* __restrict__ cout,
    const uint8_t* __restrict__ pre_in, uint8_t* __restrict__ pre_out,
    const unsigned short* __restrict__ w1h_, const unsigned short* __restrict__ w1l_,
    const unsigned short* __restrict__ w2h_, const unsigned short* __restrict__ w2l_,
    int gate) {

    __shared__ __align__(16) char smem[SMEM_BYTES];
    float* cs = (float*)smem;                       // 17 planes x 400 floats (phases A-D1)
    unsigned short* Ph = (unsigned short*)smem;     // [256][PSTR] bf16 hi  (overlays cs)
    unsigned short* Pl = Ph + PL_OFF;               // [256][PSTR] bf16 lo

    const int tid = threadIdx.x;
    const int tx = tid & 15, ty = tid >> 4;
    const int bx = blockIdx.x * TILE, by = blockIdx.y * TILE;
    const int n = blockIdx.z;
    const float* cbase = cin + (size_t)n * CH * HWSZ;
    const uint8_t* pbase = pre_in + (size_t)n * HWSZ;

    // ---- hoisted coords: full 20x20 positions (raw ch0), two per thread ----
    const int lyA = tid / 20, lxA = tid % 20;
    const int gyA = by + lyA - 2, gxA = bx + lxA - 2;
    const bool okA = ((unsigned)gyA < HH) && ((unsigned)gxA < WW);
    const int offA = gyA * WW + gxA;

    const int rB = tid + 256;                  // valid when tid < 144
    const int lyB = rB / 20, lxB = rB % 20;
    const int gyB = by + lyB - 2, gxB = bx + lxB - 2;
    const bool okB = ((unsigned)gyB < HH) && ((unsigned)gxB < WW);
    const int offB = gyB * WW + gxB;

    // ---- hoisted coords: 18x18 region positions, two per thread ----
    const int j0 = tid;                        // always < 324
    const int jy0 = j0 / 18, jx0 = j0 % 18;
    const int gy0 = by + jy0 - 1, gx0 = bx + jx0 - 1;
    const bool ok0 = ((unsigned)gy0 < HH) && ((unsigned)gx0 < WW);
    const int goff0 = gy0 * WW + gx0;
    const int lpos0 = (jy0 + 1) * LW + (jx0 + 1);

    const int j1 = tid + 256;                  // valid when tid < 68
    const int jy1 = j1 / 18, jx1 = j1 % 18;
    const int gy1 = by + jy1 - 1, gx1 = bx + jx1 - 1;
    const bool ok1 = ((unsigned)gy1 < HH) && ((unsigned)gx1 < WW);
    const int goff1 = gy1 * WW + gx1;
    const int lpos1 = (jy1 + 1) * LW + (jx1 + 1);
    const bool hasB = (tid < 68);

    // ---- A: stage raw ch0 (plane 16) AND pre-issue all other global loads ----
    cs[CH * LA + tid] = okA ? cbase[offA] : 0.0f;
    if (tid < 144) cs[CH * LA + rB] = okB ? cbase[offB] : 0.0f;

    float st0[CH - 1];
    {
        const float* gp = cbase + goff0;
#pragma unroll
        for (int c = 1; c < CH; ++c) st0[c - 1] = ok0 ? gp[c * HWSZ] : 0.0f;
    }
    int pv0 = 1;
    if (gate) pv0 = ok0 ? (int)pbase[goff0] : 0;

    float st1[CH - 1];
    int pv1 = 1;
    if (hasB) {
        const float* gp = cbase + goff1;
#pragma unroll
        for (int c = 1; c < CH; ++c) st1[c - 1] = ok1 ? gp[c * HWSZ] : 0.0f;
        if (gate) pv1 = ok1 ? (int)pbase[goff1] : 0;
    }
    __syncthreads();

    // ---- B+C fused: gate factor from raw plane 16, gated writes to planes 0..15 ----
    {
        const float* rp = cs + CH * LA;
        float pm = -1e30f;
#pragma unroll
        for (int dy = -1; dy <= 1; ++dy)
#pragma unroll
            for (int dx = -1; dx <= 1; ++dx)
                pm = fmaxf(pm, rp[lpos0 + dy * LW + dx]);
        float g0 = 1.0f;
        if (gate) g0 = (pv0 && pm > THR) ? 1.0f : 0.0f;
        cs[lpos0] = rp[lpos0] * g0;
#pragma unroll
        for (int c = 1; c < CH; ++c) cs[c * LA + lpos0] = st0[c - 1] * g0;
    }
    if (hasB) {
        const float* rp = cs + CH * LA;
        float pm = -1e30f;
#pragma unroll
        for (int dy = -1; dy <= 1; ++dy)
#pragma unroll
            for (int dx = -1; dx <= 1; ++dx)
                pm = fmaxf(pm, rp[lpos1 + dy * LW + dx]);
        float g1 = 1.0f;
        if (gate) g1 = (pv1 && pm > THR) ? 1.0f : 0.0f;
        cs[lpos1] = rp[lpos1] * g1;
#pragma unroll
        for (int c = 1; c < CH; ++c) cs[c * LA + lpos1] = st1[c - 1] * g1;
    }
    __syncthreads();

    // ---- D1: pre(i) bits + per-thread perception (reads cs) ----
    const int base = (ty + 2) * LW + (tx + 2);
    float pm = -1e30f;
#pragma unroll
    for (int dy = -1; dy <= 1; ++dy)
#pragma unroll
        for (int dx = -1; dx <= 1; ++dx)
            pm = fmaxf(pm, cs[base + dy * LW + dx]);
    pre_out[(size_t)n * HWSZ + (size_t)(by + ty) * WW + (bx + tx)] = (pm > THR) ? 1 : 0;

    float p[48];
    perception_at(cs, base, p);
    __syncthreads();   // all cs reads done; P may now overlay cs

    // ---- D2: split p -> bf16 hi/lo into LDS (row = tid = pixel py*16+px) ----
    {
        unsigned short* hrow = Ph + tid * PSTR;
        unsigned short* lrow = Pl + tid * PSTR;
#pragma unroll
        for (int j = 0; j < 12; ++j) {
            sh4 hv, lv;
            float f0 = p[4 * j + 0], f1 = p[4 * j + 1], f2 = p[4 * j + 2], f3 = p[4 * j + 3];
            unsigned short h0 = f2bf(f0), h1 = f2bf(f1), h2 = f2bf(f2), h3 = f2bf(f3);
            hv.x = (short)h0; hv.y = (short)h1; hv.z = (short)h2; hv.w = (short)h3;
            lv.x = (short)f2bf(f0 - bf2f(h0));
            lv.y = (short)f2bf(f1 - bf2f(h1));
            lv.z = (short)f2bf(f2 - bf2f(h2));
            lv.w = (short)f2bf(f3 - bf2f(h3));
            *(sh4*)(hrow + 4 * j) = hv;
            *(sh4*)(lrow + 4 * j) = lv;
        }
    }
    __syncthreads();

    // ---- D3: h = relu(w1 x P) via MFMA, split-bf16 3-product ----
    const int lane = tid & 63;
    const int wv = tid >> 6;            // wave id: pixels [64*wv, 64*wv+64)
    const int px = lane & 15;           // N-col within tile / A-row within tile
    const int kc = lane >> 4;           // k-chunk id (0..3)
    const sh4 z4 = (sh4)0;
    const bf16x8 zero8 = mk8(z4, z4);

    f32x4 acc[3][4];
#pragma unroll
    for (int m = 0; m < 3; ++m)
#pragma unroll
        for (int t = 0; t < 4; ++t) acc[m][t] = 0.0f;

#pragma unroll
    for (int m = 0; m < 3; ++m) {
        const unsigned short* ah = w1h_ + (16 * m + px) * 48;
        const unsigned short* al = w1l_ + (16 * m + px) * 48;
        bf16x8 Ah1 = mk8(lds4(ah + 8 * kc), lds4(ah + 8 * kc + 4));
        bf16x8 Ah2 = mk8(lds4(ah + 32 + 8 * kc), lds4(ah + 36 + 8 * kc));  // padded buf; garbage for kc>=2 ok
        bf16x8 Al1 = mk8(lds4(al + 8 * kc), lds4(al + 8 * kc + 4));
        bf16x8 Al2 = mk8(lds4(al + 32 + 8 * kc), lds4(al + 36 + 8 * kc));
#pragma unroll
        for (int t = 0; t < 4; ++t) {
            const int pix = 64 * wv + 16 * t + px;
            const unsigned short* bh = Ph + pix * PSTR;
            const unsigned short* bl = Pl + pix * PSTR;
            bf16x8 Bh1 = mk8(lds4(bh + 8 * kc), lds4(bh + 8 * kc + 4));
            bf16x8 Bl1 = mk8(lds4(bl + 8 * kc), lds4(bl + 8 * kc + 4));
            bf16x8 Bh2 = (kc < 2) ? mk8(lds4(bh + 32 + 8 * kc), lds4(bh + 36 + 8 * kc)) : zero8;
            bf16x8 Bl2 = (kc < 2) ? mk8(lds4(bl + 32 + 8 * kc), lds4(bl + 36 + 8 * kc)) : zero8;
            f32x4 a = acc[m][t];
            a = __builtin_amdgcn_mfma_f32_16x16x32_bf16(Al1, Bh1, a, 0, 0, 0);
            a = __builtin_amdgcn_mfma_f32_16x16x32_bf16(Ah1, Bl1, a, 0, 0, 0);
            a = __builtin_amdgcn_mfma_f32_16x16x32_bf16(Ah1, Bh1, a, 0, 0, 0);
            a = __builtin_amdgcn_mfma_f32_16x16x32_bf16(Al2, Bh2, a, 0, 0, 0);
            a = __builtin_amdgcn_mfma_f32_16x16x32_bf16(Ah2, Bl2, a, 0, 0, 0);
            a = __builtin_amdgcn_mfma_f32_16x16x32_bf16(Ah2, Bh2, a, 0, 0, 0);
            acc[m][t] = a;
        }
    }

    // residual = gated center state (P[pix][ch], ch = 4*kc + r) -- read before H overlay
    float res[4][4];
#pragma unroll
    for (int t = 0; t < 4; ++t) {
        const int pix = 64 * wv + 16 * t + px;
        sh4 rh = lds4(Ph + pix * PSTR + 4 * kc);
        sh4 rl = lds4(Pl + pix * PSTR + 4 * kc);
        res[t][0] = bf2f((unsigned short)rh.x) + bf2f((unsigned short)rl.x);
        res[t][1] = bf2f((unsigned short)rh.y) + bf2f((unsigned short)rl.y);
        res[t][2] = bf2f((unsigned short)rh.z) + bf2f((unsigned short)rl.z);
        res[t][3] = bf2f((unsigned short)rh.w) + bf2f((unsigned short)rl.w);
    }
    __syncthreads();   // everyone done reading P

    // ---- D4: h = relu(acc) -> bf16, overlaying Ph. lane holds q = 16m+4*kc+r, pixel 16t+px ----
#pragma unroll
    for (int t = 0; t < 4; ++t) {
        const int pix = 64 * wv + 16 * t + px;
        unsigned short* hrow = Ph + pix * PSTR;
#pragma unroll
        for (int m = 0; m < 3; ++m) {
            f32x4 a = acc[m][t];
            sh4 hv;
            hv.x = (short)f2bf(fmaxf(a[0], 0.0f));
            hv.y = (short)f2bf(fmaxf(a[1], 0.0f));
            hv.z = (short)f2bf(fmaxf(a[2], 0.0f));
            hv.w = (short)f2bf(fmaxf(a[3], 0.0f));
            *(sh4*)(hrow + 16 * m + 4 * kc) = hv;
        }
    }
    __syncthreads();

    // ---- D5: cur = w2 x h (2-product: (W2h+W2l) x Hbf16) + residual; store ----
    {
        const unsigned short* ah = w2h_ + px * 48;
        const unsigned short* al = w2l_ + px * 48;
        bf16x8 A2h1 = mk8(lds4(ah + 8 * kc), lds4(ah + 8 * kc + 4));
        bf16x8 A2h2 = mk8(lds4(ah + 32 + 8 * kc), lds4(ah + 36 + 8 * kc));
        bf16x8 A2l1 = mk8(lds4(al + 8 * kc), lds4(al + 8 * kc + 4));
        bf16x8 A2l2 = mk8(lds4(al + 32 + 8 * kc), lds4(al + 36 + 8 * kc));

        f32x4 q[4];
#pragma unroll
        for (int t = 0; t < 4; ++t) q[t] = 0.0f;
#pragma unroll
        for (int t = 0; t < 4; ++t) {
            const int pix = 64 * wv + 16 * t + px;
            const unsigned short* bh = Ph + pix * PSTR;
            bf16x8 B1 = mk8(lds4(bh + 8 * kc), lds4(bh + 8 * kc + 4));
            bf16x8 B2 = (kc < 2) ? mk8(lds4(bh + 32 + 8 * kc), lds4(bh + 36 + 8 * kc)) : zero8;
            f32x4 a = q[t];
            a = __builtin_amdgcn_mfma_f32_16x16x32_bf16(A2l1, B1, a, 0, 0, 0);
            a = __builtin_amdgcn_mfma_f32_16x16x32_bf16(A2h1, B1, a, 0, 0, 0);
            a = __builtin_amdgcn_mfma_f32_16x16x32_bf16(A2l2, B2, a, 0, 0, 0);
            a = __builtin_amdgcn_mfma_f32_16x16x32_bf16(A2h2, B2, a, 0, 0, 0);
            q[t] = a;
        }

        float* ob = cout + (size_t)n * CH * HWSZ;
#pragma unroll
        for (int t = 0; t < 4; ++t) {
            const int rowoff = (by + 4 * wv + t) * WW + bx + px;
#pragma unroll
            for (int r = 0; r < 4; ++r)
                ob[(size_t)(4 * kc + r) * HWSZ + rowoff] = q[t][r] + res[t][r];
        }
    }
}

// ---------------- final: apply gate(30), emit channels 1..10 ----------------
__global__ __launch_bounds__(256) void final_kernel(
    const float* __restrict__ cur, const uint8_t* __restrict__ pre,
    float* __restrict__ out) {
    int i = blockIdx.x * 256 + threadIdx.x;        // over NIMG*H*W
    if (i >= NIMG * HWSZ) return;
    int x = i % WW, y = (i / WW) % HH, n = i / HWSZ;
    const float* c0 = cur + (size_t)n * CH * HWSZ;
    float pm = -1e30f;
    for (int dy = -1; dy <= 1; ++dy) {
        int yy = y + dy;
        if ((unsigned)yy >= HH) continue;
        for (int dx = -1; dx <= 1; ++dx) {
            int xx = x + dx;
            if ((unsigned)xx >= WW) continue;
            pm = fmaxf(pm, c0[yy * WW + xx]);
        }
    }
    const bool alive = pre[i] && (pm > THR);
    float* ob = out + (size_t)n * 10 * HWSZ + y * WW + x;
#pragma unroll
    for (int k = 1; k <= 10; ++k)
        ob[(k - 1) * HWSZ] = alive ? c0[k * HWSZ + y * WW + x] : 0.0f;
}

extern "C" void kernel_launch(void* const* d_in, const int* in_sizes, int n_in,
                              void* d_out, int out_size, void* d_ws, size_t ws_size,
                              hipStream_t stream) {
    const float* inp = (const float*)d_in[0];
    const float* w1  = (const float*)d_in[1];
    const float* w2  = (const float*)d_in[2];
    float* out = (float*)d_out;

    const size_t SE = (size_t)NIMG * CH * HWSZ;    // 8,388,608 floats
    float* bufA = (float*)d_ws;
    float* bufB = bufA + SE;
    uint8_t* bitsA = (uint8_t*)(bufB + SE);
    uint8_t* bitsB = bitsA + (size_t)NIMG * HWSZ;
    // weight fragments (bf16), padded +32/+32 shorts so chunk-2 A reads past row 47/15 stay in-bounds
    unsigned short* w1h = (unsigned short*)(bitsB + (size_t)NIMG * HWSZ);
    unsigned short* w1l = w1h + (48 * 48 + 32);
    unsigned short* w2h = w1l + (48 * 48 + 32);
    unsigned short* w2l = w2h + (16 * 48 + 32);

    init_kernel<<<((int)SE + 255) / 256, 256, 0, stream>>>(inp, bufA);
    prepack<<<1, 256, 0, stream>>>(w1, w2, w1h, w1l, w2h, w2l);

    dim3 grid(WW / TILE, HH / TILE, NIMG);
    float* src = bufA;
    float* dst = bufB;
    uint8_t* pin = bitsB;   // unused on first iter (gate=0)
    uint8_t* pout = bitsA;
    for (int it = 0; it < NUM_ITER; ++it) {
        step_kernel<<<grid, 256, 0, stream>>>(src, dst, pin, pout,
                                              w1h, w1l, w2h, w2l,
                                              it == 0 ? 0 : 1);
        float* t = src; src = dst; dst = t;
        uint8_t* tb = pin; pin = pout; pout = tb;
    }
    // after loop: src = cur(30), pin = pre(30) bits
    final_kernel<<<(NIMG * HWSZ + 255) / 256, 256, 0, stream>>>(src, pin, out);
}